// Round 4
// baseline (709.966 us; speedup 1.0000x reference)
//
#include <hip/hip_runtime.h>
#include <hip/hip_bf16.h>

#define N_NODES 50000
#define N_EDGES 600000
#define D_IN    128
#define D_HID   1024
#define D_OUT   128

// ---------------------------------------------------------------------------
// Workspace layout (bytes):
//   featb  : [N_NODES*128] bf16   @ 0            (12,800,000)
//   eid    : [N_EDGES] int        @ 12,800,000   ( 2,400,000)
//   off    : [N_NODES+1] int      @ 15,200,000   (   200,016)
//   cursor : [N_NODES] int        @ 15,400,016   (   200,000)
//   deg    : [N_NODES] int        @ 15,600,016   (   200,000)
//   bsum   : [256] int            @ 15,800,016   (     1,024)
//   W1T    : [1024*128] bf16      @ 15,801,040   (   262,144)   [n][k]
//   W2T    : [128*1024] bf16      @ 16,063,184   (   262,144)   [n][k]
// ---------------------------------------------------------------------------
#define WS_FEATB  0
#define WS_EID    12800000
#define WS_OFF    15200000
#define WS_CURSOR 15400016
#define WS_DEG    15600016
#define WS_BSUM   15800016
#define WS_W1T    15801040
#define WS_W2T    16063184

typedef short bf16x8 __attribute__((ext_vector_type(8)));
typedef float f32x4  __attribute__((ext_vector_type(4)));

__device__ __forceinline__ float bf2f(unsigned short u) {
    union { unsigned int i; float f; } v; v.i = ((unsigned int)u) << 16; return v.f;
}
__device__ __forceinline__ unsigned short f2bf(float x) {
    __hip_bfloat16 b = __float2bfloat16(x);
    return *(unsigned short*)&b;
}

// ---------------------------------------------------------------------------
// CSR step 1: histogram of dst
// ---------------------------------------------------------------------------
__global__ __launch_bounds__(256) void hist_kernel(
    const int* __restrict__ dst, int* __restrict__ deg)
{
    int e = blockIdx.x * blockDim.x + threadIdx.x;
    if (e < N_EDGES) atomicAdd(&deg[dst[e]], 1);
}

// ---------------------------------------------------------------------------
// CSR step 2a: per-block sums of deg. 196 blocks x 256.
// ---------------------------------------------------------------------------
#define SCAN_NB 196
__global__ __launch_bounds__(256) void scan1_kernel(
    const int* __restrict__ deg, int* __restrict__ bsum)
{
    __shared__ int red[256];
    int t = threadIdx.x;
    int idx = blockIdx.x * 256 + t;
    red[t] = (idx < N_NODES) ? deg[idx] : 0;
    __syncthreads();
    for (int s = 128; s > 0; s >>= 1) {
        if (t < s) red[t] += red[t + s];
        __syncthreads();
    }
    if (t == 0) bsum[blockIdx.x] = red[0];
}

// ---------------------------------------------------------------------------
// CSR step 2b: exclusive scan of block sums; off[N_NODES] = total.
// ---------------------------------------------------------------------------
__global__ __launch_bounds__(256) void scan2_kernel(
    int* __restrict__ bsum, int* __restrict__ off)
{
    __shared__ int sh[256];
    int t = threadIdx.x;
    int v = (t < SCAN_NB) ? bsum[t] : 0;
    sh[t] = v;
    __syncthreads();
    for (int ofs = 1; ofs < 256; ofs <<= 1) {
        int u = (t >= ofs) ? sh[t - ofs] : 0;
        __syncthreads();
        sh[t] += u;
        __syncthreads();
    }
    if (t < SCAN_NB) bsum[t] = sh[t] - v;       // exclusive
    if (t == 255) off[N_NODES] = sh[255];       // total == N_EDGES
}

// ---------------------------------------------------------------------------
// CSR step 2c: block-local scan + block offset -> off[], cursor[]
// ---------------------------------------------------------------------------
__global__ __launch_bounds__(256) void scan3_kernel(
    const int* __restrict__ deg, const int* __restrict__ bsum,
    int* __restrict__ off, int* __restrict__ cursor)
{
    __shared__ int sh[256];
    int t = threadIdx.x;
    int idx = blockIdx.x * 256 + t;
    int v = (idx < N_NODES) ? deg[idx] : 0;
    sh[t] = v;
    __syncthreads();
    for (int ofs = 1; ofs < 256; ofs <<= 1) {
        int u = (t >= ofs) ? sh[t - ofs] : 0;
        __syncthreads();
        sh[t] += u;
        __syncthreads();
    }
    if (idx < N_NODES) {
        int ex = bsum[blockIdx.x] + sh[t] - v;
        off[idx] = ex;
        cursor[idx] = ex;
    }
}

// ---------------------------------------------------------------------------
// CSR step 3: drop edge ids into dst buckets
// ---------------------------------------------------------------------------
__global__ __launch_bounds__(256) void fill_kernel(
    const int* __restrict__ dst, int* __restrict__ cursor, int* __restrict__ eid)
{
    int e = blockIdx.x * blockDim.x + threadIdx.x;
    if (e < N_EDGES) {
        int pos = atomicAdd(&cursor[dst[e]], 1);
        eid[pos] = e;
    }
}

// ---------------------------------------------------------------------------
// Merged convert kernel:
//   blocks [0,128)   : W1 [128][1024] -> W1T [1024][128] bf16  (32x4 tiles)
//   blocks [128,256) : W2 [1024][128] -> W2T [128][1024] bf16  (4x32 tiles)
//   blocks [256,6506): feat f32 -> bf16 straight convert (1024 elem/block)
// ---------------------------------------------------------------------------
__global__ __launch_bounds__(256) void cvt_kernel(
    const float* __restrict__ W1, const float* __restrict__ W2,
    const float* __restrict__ feat,
    unsigned short* __restrict__ w1t, unsigned short* __restrict__ w2t,
    unsigned short* __restrict__ featb)
{
    __shared__ float tile[32][33];
    int b = blockIdx.x;
    if (b < 256) {
        const float* in;
        unsigned short* outp;
        int rows, cols, c0, r0;
        if (b < 128) { in = W1; outp = w1t; rows = 128;  cols = 1024; c0 = (b & 31) * 32;        r0 = (b >> 5) * 32; }
        else         { in = W2; outp = w2t; rows = 1024; cols = 128;  c0 = ((b - 128) & 3) * 32; r0 = ((b - 128) >> 2) * 32; }
        int tx = threadIdx.x & 31, ty = threadIdx.x >> 5;   // ty 0..7
        #pragma unroll
        for (int i = 0; i < 32; i += 8)
            tile[ty + i][tx] = in[(size_t)(r0 + ty + i) * cols + c0 + tx];
        __syncthreads();
        #pragma unroll
        for (int i = 0; i < 32; i += 8)
            outp[(size_t)(c0 + ty + i) * rows + r0 + tx] = f2bf(tile[tx][ty + i]);
    } else {
        size_t base = (size_t)(b - 256) * 1024 + (size_t)threadIdx.x * 4;
        float4 v = *(const float4*)(feat + base);
        ushort4 o;
        o.x = f2bf(v.x); o.y = f2bf(v.y); o.z = f2bf(v.z); o.w = f2bf(v.w);
        *(ushort4*)(featb + base) = o;
    }
}

// ---------------------------------------------------------------------------
// Fused gather + 2-layer MFMA MLP. 64 nodes per block, 4 waves.
// Gather: wave w owns rows w*16..w*16+15; lane = (parity p = lane>>5,
//   column group c = lane&31 holding float4). Wave covers 2 edges per load
//   instruction (1 KB). Cross-half __shfl_xor combine, bf16 -> h_s.
// Then: layer1 MFMA (A=h_s regs, B=W1T), relu -> q_s, layer2 MFMA (B=W2T).
// ---------------------------------------------------------------------------
#define HS_STRIDE 136   // shorts per h_s row
#define QS_STRIDE 72    // shorts per q_s row

__global__ __launch_bounds__(256) void fused_gnn_kernel(
    const unsigned short* __restrict__ featb,  // [N][128] bf16
    const float* __restrict__ edge_feat,       // [E][128] f32
    const int*   __restrict__ src,
    const int*   __restrict__ eid,
    const int*   __restrict__ off,
    const unsigned short* __restrict__ w1s,    // [1024][128] bf16
    const float* __restrict__ b1,
    const unsigned short* __restrict__ w2s,    // [128][1024] bf16
    const float* __restrict__ b2,
    float* __restrict__ out)                   // [N][128] f32
{
    __shared__ __align__(16) short h_s[64 * HS_STRIDE];  // 17.4 KB
    __shared__ __align__(16) short q_s[64 * QS_STRIDE];  //  9.2 KB

    const int t    = threadIdx.x;
    const int wv   = t >> 6;
    const int lane = t & 63;
    const int nb   = blockIdx.x * 64;
    const int c    = lane & 31;    // column group (4 floats)
    const int p    = lane >> 5;    // edge parity within pair

    // ================= gather phase =================
    for (int j = 0; j < 16; ++j) {
        const int r = wv * 16 + j;
        const int n = nb + r;
        float4 accA = make_float4(0.f, 0.f, 0.f, 0.f);
        float4 accB = accA;
        if (n < N_NODES) {
            int i   = off[n];
            int end = off[n + 1];
            for (; i + 3 < end; i += 4) {
                int e0 = eid[i + p];
                int e1 = eid[i + 2 + p];
                int s0 = src[e0];
                int s1 = src[e1];
                float4  f0 = ((const float4*)(edge_feat + (size_t)e0 * D_IN))[c];
                ushort4 g0 = ((const ushort4*)featb)[(size_t)s0 * 32 + c];
                float4  f1 = ((const float4*)(edge_feat + (size_t)e1 * D_IN))[c];
                ushort4 g1 = ((const ushort4*)featb)[(size_t)s1 * 32 + c];
                accA.x += f0.x + bf2f(g0.x); accA.y += f0.y + bf2f(g0.y);
                accA.z += f0.z + bf2f(g0.z); accA.w += f0.w + bf2f(g0.w);
                accB.x += f1.x + bf2f(g1.x); accB.y += f1.y + bf2f(g1.y);
                accB.z += f1.z + bf2f(g1.z); accB.w += f1.w + bf2f(g1.w);
            }
            for (; i < end; i += 2) {
                int idx = i + p;
                int e = eid[idx < end ? idx : end - 1];
                int s = src[e];
                float4  f = ((const float4*)(edge_feat + (size_t)e * D_IN))[c];
                ushort4 g = ((const ushort4*)featb)[(size_t)s * 32 + c];
                if (idx < end) {
                    accA.x += f.x + bf2f(g.x); accA.y += f.y + bf2f(g.y);
                    accA.z += f.z + bf2f(g.z); accA.w += f.w + bf2f(g.w);
                }
            }
        }
        float ax = accA.x + accB.x, ay = accA.y + accB.y;
        float az = accA.z + accB.z, aw = accA.w + accB.w;
        ax += __shfl_xor(ax, 32);
        ay += __shfl_xor(ay, 32);
        az += __shfl_xor(az, 32);
        aw += __shfl_xor(aw, 32);
        if (p == 0) {
            unsigned int lo = (unsigned int)f2bf(ax) | ((unsigned int)f2bf(ay) << 16);
            unsigned int hi = (unsigned int)f2bf(az) | ((unsigned int)f2bf(aw) << 16);
            *(uint2*)&h_s[r * HS_STRIDE + c * 4] = make_uint2(lo, hi);
        }
    }
    __syncthreads();

    // ================= MFMA MLP phase =================
    const int half = lane >> 4;    // quad 0..3
    const int lid  = lane & 15;

    bf16x8 afrag[4][4];
    #pragma unroll
    for (int mt = 0; mt < 4; ++mt)
        #pragma unroll
        for (int ks = 0; ks < 4; ++ks)
            afrag[mt][ks] = *(const bf16x8*)&h_s[(mt * 16 + lid) * HS_STRIDE + ks * 32 + half * 8];

    f32x4 acc[4][2];
    #pragma unroll
    for (int mt = 0; mt < 4; ++mt) {
        acc[mt][0] = f32x4{0.f, 0.f, 0.f, 0.f};
        acc[mt][1] = f32x4{0.f, 0.f, 0.f, 0.f};
    }

    const int ncol1 = wv * 16 + lid;

    for (int jb = 0; jb < D_HID; jb += 64) {
        // ---- layer 1 ----
        float bias = b1[jb + ncol1];
        bf16x8 bfrag[4];
        #pragma unroll
        for (int ks = 0; ks < 4; ++ks)
            bfrag[ks] = *(const bf16x8*)&w1s[(size_t)(jb + ncol1) * 128 + ks * 32 + half * 8];

        f32x4 c1[4];
        #pragma unroll
        for (int mt = 0; mt < 4; ++mt) {
            f32x4 cc = f32x4{bias, bias, bias, bias};
            #pragma unroll
            for (int ks = 0; ks < 4; ++ks)
                cc = __builtin_amdgcn_mfma_f32_16x16x32_bf16(afrag[mt][ks], bfrag[ks], cc, 0, 0, 0);
            c1[mt] = cc;
        }

        __syncthreads();   // previous chunk's q_s reads complete
        #pragma unroll
        for (int mt = 0; mt < 4; ++mt) {
            #pragma unroll
            for (int r = 0; r < 4; ++r) {
                float v = fmaxf(c1[mt][r], 0.f);
                q_s[(mt * 16 + half * 4 + r) * QS_STRIDE + wv * 16 + lid] = (short)f2bf(v);
            }
        }
        __syncthreads();

        // ---- layer 2 ----
        bf16x8 a2f[4][2];
        #pragma unroll
        for (int mt = 0; mt < 4; ++mt)
            #pragma unroll
            for (int ks = 0; ks < 2; ++ks)
                a2f[mt][ks] = *(const bf16x8*)&q_s[(mt * 16 + lid) * QS_STRIDE + ks * 32 + half * 8];

        #pragma unroll
        for (int nt = 0; nt < 2; ++nt) {
            #pragma unroll
            for (int ks = 0; ks < 2; ++ks) {
                bf16x8 b2f = *(const bf16x8*)&w2s[(size_t)(wv * 32 + nt * 16 + lid) * 1024 + jb + ks * 32 + half * 8];
                #pragma unroll
                for (int mt = 0; mt < 4; ++mt)
                    acc[mt][nt] = __builtin_amdgcn_mfma_f32_16x16x32_bf16(a2f[mt][ks], b2f, acc[mt][nt], 0, 0, 0);
            }
        }
    }

    // ---- epilogue ----
    #pragma unroll
    for (int nt = 0; nt < 2; ++nt) {
        int col = wv * 32 + nt * 16 + lid;
        float bv = b2[col];
        #pragma unroll
        for (int mt = 0; mt < 4; ++mt) {
            #pragma unroll
            for (int r = 0; r < 4; ++r) {
                int row = nb + mt * 16 + half * 4 + r;
                if (row < N_NODES)
                    out[(size_t)row * D_OUT + col] = acc[mt][nt][r] + bv;
            }
        }
    }
}

// ---------------------------------------------------------------------------
extern "C" void kernel_launch(void* const* d_in, const int* in_sizes, int n_in,
                              void* d_out, int out_size, void* d_ws, size_t ws_size,
                              hipStream_t stream) {
    const float* feat      = (const float*)d_in[0];
    const float* edge_feat = (const float*)d_in[1];
    const int*   src       = (const int*)d_in[2];
    const int*   dst       = (const int*)d_in[3];
    const float* W1        = (const float*)d_in[4];
    const float* b1        = (const float*)d_in[5];
    const float* W2        = (const float*)d_in[6];
    const float* b2        = (const float*)d_in[7];
    float* out = (float*)d_out;

    char* ws = (char*)d_ws;
    unsigned short* featb  = (unsigned short*)(ws + WS_FEATB);
    int*   eid    = (int*)(ws + WS_EID);
    int*   off    = (int*)(ws + WS_OFF);
    int*   cursor = (int*)(ws + WS_CURSOR);
    int*   deg    = (int*)(ws + WS_DEG);
    int*   bsum   = (int*)(ws + WS_BSUM);
    unsigned short* w1t = (unsigned short*)(ws + WS_W1T);
    unsigned short* w2t = (unsigned short*)(ws + WS_W2T);

    hipMemsetAsync(deg, 0, (size_t)N_NODES * sizeof(int), stream);

    // CSR build
    hist_kernel<<<(N_EDGES + 255) / 256, 256, 0, stream>>>(dst, deg);
    scan1_kernel<<<SCAN_NB, 256, 0, stream>>>(deg, bsum);
    scan2_kernel<<<1, 256, 0, stream>>>(bsum, off);
    scan3_kernel<<<SCAN_NB, 256, 0, stream>>>(deg, bsum, off, cursor);
    fill_kernel<<<(N_EDGES + 255) / 256, 256, 0, stream>>>(dst, cursor, eid);

    // weights transpose+cvt and feat cvt (one dispatch)
    cvt_kernel<<<256 + (N_NODES * D_IN) / 1024, 256, 0, stream>>>(
        W1, W2, feat, w1t, w2t, featb);

    // fused gather + MLP
    fused_gnn_kernel<<<(N_NODES + 63) / 64, 256, 0, stream>>>(
        featb, edge_feat, src, eid, off, w1t, b1, w2t, b2, out);
}